// Round 1
// baseline (943.047 us; speedup 1.0000x reference)
//
#include <hip/hip_runtime.h>
#include <hip/hip_bf16.h>

#define NB 512
#define CCH 32
#define LF 1024
#define CL (CCH * LF)  // 32768
#define BN_EPS 1e-5f

typedef __bf16 bf16x8 __attribute__((ext_vector_type(8)));
typedef __bf16 bf16x4 __attribute__((ext_vector_type(4)));
typedef float f32x4 __attribute__((ext_vector_type(4)));

// LDS plane stride: 128 rows * 8 bf16 + 8 pad elements -> 2064 B per k-octet
// plane. 2064 % 16 == 0 keeps ds_read_b128 alignment; the +8 staggers the
// per-plane bank offset by 4 words so staging ds_write_b64 spreads banks.
#define QSTRIDE 1032

// C = A @ W^T per channel. A: (NB, CCH, LF) fp32 slab (row stride CL).
// W: (CCH, 3, LF, LF). Optional BN-normalize fused into A staging
// (h_norm = h*scale[l] + shift[l]), optional ReLU in epilogue.
template <bool BNA, bool RELU>
__global__ __launch_bounds__(256, 2) void gemm_k(
    const float* __restrict__ Abase, const float* __restrict__ Wall,
    const float* __restrict__ ball, const float* __restrict__ scale,
    const float* __restrict__ shift, float* __restrict__ Out, int layer) {
  __shared__ __bf16 As[4 * QSTRIDE];
  __shared__ __bf16 Bs[4 * QSTRIDE];

  const int tid = threadIdx.x;
  const int c = blockIdx.y;
  const int mtile = blockIdx.x & 3;   // 4 tiles over batch (512/128)
  const int ntile = blockIdx.x >> 2;  // 8 tiles over features (1024/128)

  const float* A = Abase + c * LF;
  const float* Wp = Wall + (size_t)(c * 3 + layer) * LF * LF;
  const float* bias = ball + (c * 3 + layer) * LF;
  const float* scl = BNA ? scale + c * LF : nullptr;
  const float* shf = BNA ? shift + c * LF : nullptr;

  const int lane = tid & 63;
  const int wv = tid >> 6;
  const int wm = (wv & 1) * 64;  // wave's 64x64 quadrant
  const int wn = (wv >> 1) * 64;
  const int l15 = lane & 15;
  const int quad = lane >> 4;

  // staging: thread -> (row, 4-float k-segment); 8 threads cover one row's 32 k
  const int sr = tid >> 3;   // 0..31
  const int kseg = tid & 7;  // 0..7
  const int q = kseg >> 1;   // k-octet plane
  const int bsub = (kseg & 1) * 4;

  f32x4 acc[4][4] = {};

  for (int kt = 0; kt < LF / 32; ++kt) {
    const int k0 = kt * 32 + kseg * 4;

    f32x4 sc, sh;
    if (BNA) {
      sc = *(const f32x4*)(scl + k0);
      sh = *(const f32x4*)(shf + k0);
    }
#pragma unroll
    for (int i = 0; i < 4; ++i) {
      const int r = i * 32 + sr;
      f32x4 v = *(const f32x4*)(A + (size_t)(mtile * 128 + r) * CL + k0);
      if (BNA) v = v * sc + sh;
      bf16x4 o = {(__bf16)v.x, (__bf16)v.y, (__bf16)v.z, (__bf16)v.w};
      *(bf16x4*)&As[q * QSTRIDE + r * 8 + bsub] = o;
    }
#pragma unroll
    for (int i = 0; i < 4; ++i) {
      const int r = i * 32 + sr;
      f32x4 v = *(const f32x4*)(Wp + (size_t)(ntile * 128 + r) * LF + k0);
      bf16x4 o = {(__bf16)v.x, (__bf16)v.y, (__bf16)v.z, (__bf16)v.w};
      *(bf16x4*)&Bs[q * QSTRIDE + r * 8 + bsub] = o;
    }
    __syncthreads();

    bf16x8 af[4], bfr[4];
#pragma unroll
    for (int mi = 0; mi < 4; ++mi)
      af[mi] = *(const bf16x8*)&As[quad * QSTRIDE + (wm + mi * 16 + l15) * 8];
#pragma unroll
    for (int ni = 0; ni < 4; ++ni)
      bfr[ni] = *(const bf16x8*)&Bs[quad * QSTRIDE + (wn + ni * 16 + l15) * 8];
#pragma unroll
    for (int mi = 0; mi < 4; ++mi)
#pragma unroll
      for (int ni = 0; ni < 4; ++ni)
        acc[mi][ni] = __builtin_amdgcn_mfma_f32_16x16x32_bf16(
            af[mi], bfr[ni], acc[mi][ni], 0, 0, 0);
    __syncthreads();
  }

  // epilogue: D row (batch) = quad*4 + r, col (feature) = lane&15
  float* outp = Out + (size_t)c * LF;
#pragma unroll
  for (int ni = 0; ni < 4; ++ni) {
    const int feat = ntile * 128 + wn + ni * 16 + l15;
    const float bv = bias[feat];
#pragma unroll
    for (int mi = 0; mi < 4; ++mi) {
      const int row0 = mtile * 128 + wm + mi * 16 + quad * 4;
#pragma unroll
      for (int r = 0; r < 4; ++r) {
        float v = acc[mi][ni][r] + bv;
        if (RELU) v = fmaxf(v, 0.f);
        outp[(size_t)(row0 + r) * CL + feat] = v;
      }
    }
  }
}

// Per-(channel, feature) batch stats over relu'd activations; emits fused
// affine: h_norm = h*scale + shift with scale = rstd*gamma,
// shift = beta - mean*rstd*gamma. Biased variance (matches torch BN).
__global__ __launch_bounds__(256) void bn_stats(
    const float* __restrict__ H, const float* __restrict__ gamma,
    const float* __restrict__ beta, float* __restrict__ scale,
    float* __restrict__ shift, int bnlayer) {
  __shared__ float s_sum[256], s_sq[256];
  const int tid = threadIdx.x;
  const int f = tid & 63, g = tid >> 6;
  const int c = blockIdx.y;
  const int l = blockIdx.x * 64 + f;
  const float* col = H + (size_t)c * LF + l;
  float sum = 0.f, sq = 0.f;
  for (int n = g; n < NB; n += 4) {
    float v = col[(size_t)n * CL];
    sum += v;
    sq += v * v;
  }
  s_sum[tid] = sum;
  s_sq[tid] = sq;
  __syncthreads();
  if (g == 0) {
    sum = s_sum[f] + s_sum[64 + f] + s_sum[128 + f] + s_sum[192 + f];
    sq = s_sq[f] + s_sq[64 + f] + s_sq[128 + f] + s_sq[192 + f];
    const float mean = sum * (1.f / NB);
    const float var = sq * (1.f / NB) - mean * mean;
    const float rstd = rsqrtf(var + BN_EPS);
    const float ga = gamma[(size_t)(c * 2 + bnlayer) * LF + l];
    const float be = beta[(size_t)(c * 2 + bnlayer) * LF + l];
    const float sc = rstd * ga;
    scale[(size_t)c * LF + l] = sc;
    shift[(size_t)c * LF + l] = be - mean * sc;
  }
}

extern "C" void kernel_launch(void* const* d_in, const int* in_sizes, int n_in,
                              void* d_out, int out_size, void* d_ws,
                              size_t ws_size, hipStream_t stream) {
  const float* x = (const float*)d_in[0];
  const float* W = (const float*)d_in[1];
  const float* b = (const float*)d_in[2];
  const float* gamma = (const float*)d_in[3];
  const float* beta = (const float*)d_in[4];
  float* out = (float*)d_out;

  // ws layout: scale0|shift0|scale1|shift1 (C*L floats each = 512 KB), then
  // h2 activation buffer (64 MB). h1 lives in d_out (fully overwritten by
  // the final layer).
  float* scale0 = (float*)d_ws;
  float* shift0 = scale0 + CCH * LF;
  float* scale1 = shift0 + CCH * LF;
  float* shift1 = scale1 + CCH * LF;
  float* h2 = shift1 + CCH * LF;

  const dim3 blk(256);
  const dim3 ggrid(32, 32);   // 4 m-tiles * 8 n-tiles, 32 channels
  const dim3 sgrid(16, 32);   // 1024 features / 64, 32 channels

  // layer 0: h1 = relu(x @ W0^T + b0) -> d_out (scratch)
  gemm_k<false, true><<<ggrid, blk, 0, stream>>>(x, W, b, nullptr, nullptr, out, 0);
  bn_stats<<<sgrid, blk, 0, stream>>>(out, gamma, beta, scale0, shift0, 0);
  // layer 1: h2 = relu(BN(h1) @ W1^T + b1) -> ws
  gemm_k<true, true><<<ggrid, blk, 0, stream>>>(out, W, b, scale0, shift0, h2, 1);
  bn_stats<<<sgrid, blk, 0, stream>>>(h2, gamma, beta, scale1, shift1, 1);
  // layer 2: out = BN(h2) @ W2^T + b2 -> d_out
  gemm_k<true, false><<<ggrid, blk, 0, stream>>>(h2, W, b, scale1, shift1, out, 2);
}